// Round 1
// baseline (3581.421 us; speedup 1.0000x reference)
//
#include <hip/hip_runtime.h>
#include <hip/hip_bf16.h>

#define N_NODES 100000
#define F_IN 1433
#define H1F 32
#define H2F 16

typedef __bf16 bf16x8 __attribute__((ext_vector_type(8)));
typedef float f32x4 __attribute__((ext_vector_type(4)));

// ---- workspace layout (float offsets) ----
// zeroed region (one memset): h1acc, h2acc, cnt, lse_acc
#define O_H1ACC 0          // 3,200,000 f  (N*32) -> becomes h1 in-place after fin1
#define O_H2ACC 3200000    // 1,600,000 f  (N*16) -> becomes h2 in-place after fin2
#define O_CNT   4800000    // 100,000 int  (degree counts)
#define O_LSE   4900000    // 100,000 f    (sum-exp accum -> log in place)
#define ZERO_FLOATS 5000000
#define O_H1PRE 5000000    // 3,200,000 f  (x@W1)
#define O_H2PRE 8200000    // 1,600,000 f  (h1@W2)
#define O_DISQ  9800000    // 100,000 f    (deg^-1/2)
#define O_WLT   9900000    // 24,000 f     (Wl transposed [1433][16])
#define O_W1F   9924000    // 23,040 f     (W1 packed bf16 B-fragments, 46080 elems)

// ---------------- degree / normalization ----------------
__global__ void k_deg(const int* __restrict__ dst, int E, int* __restrict__ cnt) {
    int t = blockIdx.x * 256 + threadIdx.x;
    if (t < E) atomicAdd(&cnt[dst[t]], 1);
}

__global__ void k_disq(const int* __restrict__ cnt, float* __restrict__ disq) {
    int t = blockIdx.x * 256 + threadIdx.x;
    if (t < N_NODES) disq[t] = rsqrtf((float)(cnt[t] + 1));  // +1 self-loop
}

// ---------------- W1 -> bf16 B-fragment pack ----------------
// layout: [ks 0..44][ntile 0..1][lane 0..63][j 0..7]; B[k][n]: n=lane&15, k=ks*32+(lane>>4)*8+j
__global__ void k_w1f(const float* __restrict__ W1, __bf16* __restrict__ w1f) {
    int t = blockIdx.x * 256 + threadIdx.x;
    if (t >= 45 * 1024) return;
    int j = t & 7, lane = (t >> 3) & 63, nt = (t >> 9) & 1, ks = t >> 10;
    int k = ks * 32 + (lane >> 4) * 8 + j;
    int f = nt * 16 + (lane & 15);
    float v = (k < F_IN) ? W1[k * H1F + f] : 0.f;  // zero-pad K tail: A garbage * B 0 = 0
    w1f[t] = (__bf16)v;
}

// ---------------- Wl transpose: wlt[j*16+k] = Wl[k*F_IN+j] ----------------
__global__ void k_wlt(const float* __restrict__ Wl, float* __restrict__ wlt) {
    int t = blockIdx.x * 256 + threadIdx.x;
    if (t < F_IN * H2F) {
        int j = t >> 4, k = t & 15;
        wlt[t] = Wl[k * F_IN + j];
    }
}

// ---------------- GEMM1: h1pre = x @ W1  (bf16 MFMA, A direct from global) ----------------
__global__ __launch_bounds__(256) void k_gemm1(const float* __restrict__ x,
                                               const __bf16* __restrict__ w1f,
                                               float* __restrict__ h1pre) {
    const int lane = threadIdx.x & 63;
    const int wv   = threadIdx.x >> 6;
    const int l16  = lane & 15, quad = lane >> 4;
    const int rowb = blockIdx.x * 128 + wv * 32;     // wave owns 32 rows (2 m-tiles)
    const long r0 = min(rowb + l16, N_NODES - 1);
    const long r1 = min(rowb + 16 + l16, N_NODES - 1);
    const float* xr0 = x + r0 * F_IN;
    const float* xr1 = x + r1 * F_IN;
    f32x4 acc00 = {0,0,0,0}, acc01 = {0,0,0,0}, acc10 = {0,0,0,0}, acc11 = {0,0,0,0};
    const bf16x8* bfp = (const bf16x8*)w1f;

    for (int ks = 0; ks < 45; ks++) {
        int kb = ks * 32 + quad * 8;
        bf16x8 a0, a1;
#pragma unroll
        for (int j = 0; j < 8; j++) {
            int k = kb + j; k = k > (F_IN - 1) ? (F_IN - 1) : k;  // clamped: B=0 past 1432
            a0[j] = (__bf16)xr0[k];
            a1[j] = (__bf16)xr1[k];
        }
        bf16x8 b0 = bfp[(ks * 2 + 0) * 64 + lane];
        bf16x8 b1 = bfp[(ks * 2 + 1) * 64 + lane];
        acc00 = __builtin_amdgcn_mfma_f32_16x16x32_bf16(a0, b0, acc00, 0, 0, 0);
        acc01 = __builtin_amdgcn_mfma_f32_16x16x32_bf16(a0, b1, acc01, 0, 0, 0);
        acc10 = __builtin_amdgcn_mfma_f32_16x16x32_bf16(a1, b0, acc10, 0, 0, 0);
        acc11 = __builtin_amdgcn_mfma_f32_16x16x32_bf16(a1, b1, acc11, 0, 0, 0);
    }
    // C/D: col = lane&15 (=f), row = quad*4 + reg (node offset in tile)
#pragma unroll
    for (int reg = 0; reg < 4; reg++) {
        int m0 = rowb + quad * 4 + reg;
        int m1 = m0 + 16;
        if (m0 < N_NODES) {
            h1pre[(long)m0 * 32 + l16]      = acc00[reg];
            h1pre[(long)m0 * 32 + 16 + l16] = acc01[reg];
        }
        if (m1 < N_NODES) {
            h1pre[(long)m1 * 32 + l16]      = acc10[reg];
            h1pre[(long)m1 * 32 + 16 + l16] = acc11[reg];
        }
    }
}

// ---------------- scatter layer1: h1acc[d] += norm * h1pre[s]  (32 feats) ----------------
__global__ void k_scatter1(const int* __restrict__ src, const int* __restrict__ dst,
                           const float* __restrict__ disq, const float* __restrict__ h1pre,
                           float* __restrict__ h1acc, int E) {
    long t = (long)blockIdx.x * 256 + threadIdx.x;
    if (t >= (long)E * 8) return;
    int e = (int)(t >> 3), q = (int)(t & 7);
    int s = src[e], d = dst[e];
    float w = disq[s] * disq[d];
    float4 v = ((const float4*)(h1pre + (long)s * 32))[q];
    float* p = h1acc + (long)d * 32 + q * 4;
    unsafeAtomicAdd(p + 0, w * v.x);
    unsafeAtomicAdd(p + 1, w * v.y);
    unsafeAtomicAdd(p + 2, w * v.z);
    unsafeAtomicAdd(p + 3, w * v.w);
}

// ---------------- finalize1: h1 = relu(h1acc + (1/deg)*h1pre + b1)  (in place) ----------------
__global__ void k_fin1(float* __restrict__ h1acc, const float* __restrict__ h1pre,
                       const float* __restrict__ disq, const float* __restrict__ b1) {
    int t = blockIdx.x * 256 + threadIdx.x;
    if (t >= N_NODES * 32) return;
    int n = t >> 5, f = t & 31;
    float iq = disq[n];
    float v = h1acc[t] + iq * iq * h1pre[t] + b1[f];
    h1acc[t] = v > 0.f ? v : 0.f;
}

// ---------------- GEMM2: h2pre = h1 @ W2 ----------------
__global__ void k_gemm2(const float* __restrict__ h1, const float* __restrict__ W2,
                        float* __restrict__ h2pre) {
    int t = blockIdx.x * 256 + threadIdx.x;
    if (t >= N_NODES * 16) return;
    int n = t >> 4, f = t & 15;
    const float4* hv = (const float4*)(h1 + (long)n * 32);
    float acc = 0.f;
#pragma unroll
    for (int kq = 0; kq < 8; kq++) {
        float4 h = hv[kq];
        acc += h.x * W2[(kq * 4 + 0) * 16 + f] + h.y * W2[(kq * 4 + 1) * 16 + f]
             + h.z * W2[(kq * 4 + 2) * 16 + f] + h.w * W2[(kq * 4 + 3) * 16 + f];
    }
    h2pre[t] = acc;
}

// ---------------- scatter layer2 (16 feats) ----------------
__global__ void k_scatter2(const int* __restrict__ src, const int* __restrict__ dst,
                           const float* __restrict__ disq, const float* __restrict__ h2pre,
                           float* __restrict__ h2acc, int E) {
    long t = (long)blockIdx.x * 256 + threadIdx.x;
    if (t >= (long)E * 4) return;
    int e = (int)(t >> 2), q = (int)(t & 3);
    int s = src[e], d = dst[e];
    float w = disq[s] * disq[d];
    float4 v = ((const float4*)(h2pre + (long)s * 16))[q];
    float* p = h2acc + (long)d * 16 + q * 4;
    unsafeAtomicAdd(p + 0, w * v.x);
    unsafeAtomicAdd(p + 1, w * v.y);
    unsafeAtomicAdd(p + 2, w * v.z);
    unsafeAtomicAdd(p + 3, w * v.w);
}

// ---------------- finalize2 ----------------
__global__ void k_fin2(float* __restrict__ h2acc, const float* __restrict__ h2pre,
                       const float* __restrict__ disq, const float* __restrict__ b2) {
    int t = blockIdx.x * 256 + threadIdx.x;
    if (t >= N_NODES * 16) return;
    int n = t >> 4, f = t & 15;
    float iq = disq[n];
    float v = h2acc[t] + iq * iq * h2pre[t] + b2[f];
    h2acc[t] = v > 0.f ? v : 0.f;
}

// ---------------- stats: lse_acc[n] += sum_j exp(logit[n][j]) over j-chunk ----------------
// lane = node (4 nodes per lane), wave = 256 nodes; max-free logsumexp (|logit| <~ 2)
__global__ __launch_bounds__(256) void k_stats(const float* __restrict__ h2,
                                               const float* __restrict__ wlt,
                                               const float* __restrict__ bl,
                                               float* __restrict__ lseacc) {
    int wv = threadIdx.x >> 6, lane = threadIdx.x & 63;
    int jc = blockIdx.x;                 // 0..7
    int nw = blockIdx.y * 4 + wv;        // node-wave id
    int j0 = jc * 180, j1 = min(j0 + 180, F_IN);
    int nb = nw * 256 + lane;
    float hr[4][16];
    float acc[4] = {0.f, 0.f, 0.f, 0.f};
#pragma unroll
    for (int i = 0; i < 4; i++) {
        long n = min(nb + 64 * i, N_NODES - 1);
        const float4* hv = (const float4*)(h2 + n * 16);
#pragma unroll
        for (int q = 0; q < 4; q++) {
            float4 h = hv[q];
            hr[i][q * 4 + 0] = h.x; hr[i][q * 4 + 1] = h.y;
            hr[i][q * 4 + 2] = h.z; hr[i][q * 4 + 3] = h.w;
        }
    }
    for (int j = j0; j < j1; j++) {
        const float4* wv4 = (const float4*)(wlt + j * 16);
        float wk[16];
#pragma unroll
        for (int q = 0; q < 4; q++) {
            float4 w = wv4[q];
            wk[q * 4 + 0] = w.x; wk[q * 4 + 1] = w.y; wk[q * 4 + 2] = w.z; wk[q * 4 + 3] = w.w;
        }
        float b = bl[j];
#pragma unroll
        for (int i = 0; i < 4; i++) {
            float lg = b;
#pragma unroll
            for (int k = 0; k < 16; k++) lg += hr[i][k] * wk[k];
            acc[i] += __expf(lg);
        }
    }
#pragma unroll
    for (int i = 0; i < 4; i++) {
        int n = nb + 64 * i;
        if (n < N_NODES) unsafeAtomicAdd(&lseacc[n], acc[i]);
    }
}

__global__ void k_lse(float* __restrict__ lse) {
    int t = blockIdx.x * 256 + threadIdx.x;
    if (t < N_NODES) lse[t] = __logf(lse[t]);
}

// ---------------- passB: out[n][j] = logit - lse[n]  (column-stationary, coalesced stores) ----
__global__ __launch_bounds__(256) void k_passb(const float* __restrict__ h2,
                                               const float* __restrict__ Wl,
                                               const float* __restrict__ bl,
                                               const float* __restrict__ lse,
                                               float* __restrict__ out) {
    int wv = threadIdx.x >> 6, lane = threadIdx.x & 63;
    int tile = blockIdx.x;               // 0..5, 256 cols each
    float wf[4][16], bias[4];
    int cols[4]; bool cv[4];
#pragma unroll
    for (int c = 0; c < 4; c++) {
        int col = tile * 256 + c * 64 + lane;
        cv[c] = col < F_IN;
        int cc = min(col, F_IN - 1);
        cols[c] = cc;
        bias[c] = bl[cc];
#pragma unroll
        for (int k = 0; k < 16; k++) wf[c][k] = Wl[k * F_IN + cc];
    }
    int n0 = (blockIdx.y * 4 + wv) * 128;
    for (int i = 0; i < 128; i++) {
        int n = n0 + i;
        if (n >= N_NODES) break;
        const float4* hv = (const float4*)(h2 + (long)n * 16);
        float4 h0 = hv[0], h1v = hv[1], h2v = hv[2], h3v = hv[3];
        float l = lse[n];
        float* op = out + (long)n * F_IN;
#pragma unroll
        for (int c = 0; c < 4; c++) {
            float lg = bias[c]
                + h0.x * wf[c][0]  + h0.y * wf[c][1]  + h0.z * wf[c][2]  + h0.w * wf[c][3]
                + h1v.x * wf[c][4] + h1v.y * wf[c][5] + h1v.z * wf[c][6] + h1v.w * wf[c][7]
                + h2v.x * wf[c][8] + h2v.y * wf[c][9] + h2v.z * wf[c][10]+ h2v.w * wf[c][11]
                + h3v.x * wf[c][12]+ h3v.y * wf[c][13]+ h3v.z * wf[c][14]+ h3v.w * wf[c][15];
            if (cv[c]) op[cols[c]] = lg - l;
        }
    }
}

extern "C" void kernel_launch(void* const* d_in, const int* in_sizes, int n_in,
                              void* d_out, int out_size, void* d_ws, size_t ws_size,
                              hipStream_t stream) {
    const float* x  = (const float*)d_in[0];
    const float* W1 = (const float*)d_in[1];
    const float* b1 = (const float*)d_in[2];
    const float* W2 = (const float*)d_in[3];
    const float* b2 = (const float*)d_in[4];
    const float* Wl = (const float*)d_in[5];
    const float* bl = (const float*)d_in[6];
    const int*   ei = (const int*)d_in[7];
    const int E = in_sizes[7] / 2;
    const int* srcp = ei;
    const int* dstp = ei + E;

    float* ws    = (float*)d_ws;
    float* h1acc = ws + O_H1ACC;
    float* h2acc = ws + O_H2ACC;
    int*   cnt   = (int*)(ws + O_CNT);
    float* lse   = ws + O_LSE;
    float* h1pre = ws + O_H1PRE;
    float* h2pre = ws + O_H2PRE;
    float* disq  = ws + O_DISQ;
    float* wlt   = ws + O_WLT;
    __bf16* w1f  = (__bf16*)(ws + O_W1F);
    float* out   = (float*)d_out;

    hipMemsetAsync(ws, 0, (size_t)ZERO_FLOATS * sizeof(float), stream);

    k_deg<<<(E + 255) / 256, 256, 0, stream>>>(dstp, E, cnt);
    k_disq<<<(N_NODES + 255) / 256, 256, 0, stream>>>(cnt, disq);
    k_w1f<<<(45 * 1024 + 255) / 256, 256, 0, stream>>>(W1, w1f);
    k_wlt<<<(F_IN * H2F + 255) / 256, 256, 0, stream>>>(Wl, wlt);

    k_gemm1<<<(N_NODES + 127) / 128, 256, 0, stream>>>(x, w1f, h1pre);
    k_scatter1<<<(int)(((long)E * 8 + 255) / 256), 256, 0, stream>>>(srcp, dstp, disq, h1pre, h1acc, E);
    k_fin1<<<(N_NODES * 32 + 255) / 256, 256, 0, stream>>>(h1acc, h1pre, disq, b1);

    k_gemm2<<<(N_NODES * 16 + 255) / 256, 256, 0, stream>>>(h1acc, W2, h2pre);
    k_scatter2<<<(int)(((long)E * 4 + 255) / 256), 256, 0, stream>>>(srcp, dstp, disq, h2pre, h2acc, E);
    k_fin2<<<(N_NODES * 16 + 255) / 256, 256, 0, stream>>>(h2acc, h2pre, disq, b2);

    k_stats<<<dim3(8, 98), 256, 0, stream>>>(h2acc, wlt, bl, lse);
    k_lse<<<(N_NODES + 255) / 256, 256, 0, stream>>>(lse);
    k_passb<<<dim3(6, 196), 256, 0, stream>>>(h2acc, Wl, bl, lse, out);
}